// Round 2
// baseline (259.767 us; speedup 1.0000x reference)
//
#include <hip/hip_runtime.h>
#include <stdint.h>

#define NB 32768
#define NPASS 4
#define FULL27 0x07FFFFFFu

// layout: per puzzle, 27 words; word (d*3+b) = digit d, band b (rows 3b..3b+2),
// bit (r*9+c) with r = local row 0..2, c = column 0..8.
// BOX k mask within band: 0x1C0E07 << 3k ; COL c mask: 0x40201 << c ; ROW r: 0x1FF << 9r
// Packed word w == bits of input floats [27w .. 27w+26]  (flat order matches).

// Coalesced pack: block stages 256*27 floats -> bit bytes in LDS, then each
// thread assembles one 27-bit word from 27 LDS bytes.
__global__ __launch_bounds__(256)
void pack_kernel(const uint32_t* __restrict__ in, uint32_t* __restrict__ packed) {
    __shared__ uint8_t bits[256 * 27];
    const int tid = threadIdx.x;
    const size_t F0 = (size_t)blockIdx.x * (256 * 27);
    #pragma unroll
    for (int i = 0; i < 27; ++i) {
        size_t idx = F0 + (size_t)i * 256 + tid;
        bits[i * 256 + tid] = (in[idx] != 0u) ? 1u : 0u;  // total floats = NB*729, exact multiple of 6912
    }
    __syncthreads();
    uint32_t acc = 0;
    const int off = tid * 27;
    #pragma unroll
    for (int i = 0; i < 27; ++i)
        acc |= (uint32_t)bits[off + i] << i;
    packed[blockIdx.x * 256 + tid] = acc;
}

__global__ __launch_bounds__(64, 1)
void solve_kernel(const uint32_t* __restrict__ pin, uint32_t* __restrict__ pout,
                  float* __restrict__ solved) {
    int p = blockIdx.x * blockDim.x + threadIdx.x;
    if (p >= NB) return;
    uint32_t bd[9][3];
    {
        const uint32_t* src = pin + (size_t)p * 27;
        #pragma unroll
        for (int i = 0; i < 27; ++i) bd[i / 3][i % 3] = src[i];
    }

    for (int pass = 0; pass < NPASS; ++pass) {
        // ---------- filter 'box': solved cell eliminates digit from rest of box ----------
        {
            uint32_t on[3] = {0,0,0}, tw[3] = {0,0,0}, fo[3] = {0,0,0};
            #pragma unroll
            for (int d = 0; d < 9; ++d)
                #pragma unroll
                for (int b = 0; b < 3; ++b) {
                    uint32_t c = on[b] & bd[d][b];
                    on[b] ^= bd[d][b];
                    fo[b] |= tw[b] & c;
                    tw[b] ^= c;
                }
            uint32_t ex1[3];
            #pragma unroll
            for (int b = 0; b < 3; ++b) ex1[b] = on[b] & ~tw[b] & ~fo[b];
            #pragma unroll
            for (int d = 0; d < 9; ++d)
                #pragma unroll
                for (int b = 0; b < 3; ++b) {
                    uint32_t s = bd[d][b] & ex1[b];
                    #pragma unroll
                    for (int k = 0; k < 3; ++k) {
                        uint32_t bm = 0x1C0E07u << (3 * k);
                        uint32_t sm = s & bm;
                        uint32_t multi = sm & (sm - 1u);
                        // 0 solved: keep all; 1 solved: keep only it; >=2: clear whole box
                        uint32_t keep = (sm == 0u) ? 0xFFFFFFFFu : (~bm | (multi ? 0u : sm));
                        bd[d][b] &= keep;
                    }
                }
        }

        // ---------- pointing 'h': box candidates confined to one row ----------
        #pragma unroll
        for (int d = 0; d < 9; ++d)
            #pragma unroll
            for (int b = 0; b < 3; ++b) {
                uint32_t w = bd[d][b];
                uint32_t t = (w | (w >> 1) | (w >> 2)) & 0x01249249u;   // presence(r,k) at bit 9r+3k
                uint32_t sum = (t & 0x1FFu) + ((t >> 9) & 0x1FFu) + ((t >> 18) & 0x1FFu); // rows-per-box at [3k,3k+1]
                uint32_t single = sum & ~(sum >> 1) & 0x49u;            // nrows==1 at bit 3k
                uint32_t point = t & (single * 0x40201u);
                uint32_t clearm = 0;
                #pragma unroll
                for (int r = 0; r < 3; ++r) {
                    uint32_t pr = (point >> (9 * r)) & 0x1FFu;          // pointing boxes of row r at bits 0,3,6
                    uint32_t multi = pr & (pr - 1u);
                    uint32_t segkeep = multi ? 0u : pr * 7u;            // sole pointing box keeps its segment
                    uint32_t rc = pr ? ((0x1FFu & ~segkeep) << (9 * r)) : 0u;
                    clearm |= rc;
                }
                bd[d][b] = w & ~clearm;
            }

        // ---------- pointing 'v': box candidates confined to one column ----------
        #pragma unroll
        for (int d = 0; d < 9; ++d) {
            uint32_t pnt[3];
            #pragma unroll
            for (int b = 0; b < 3; ++b) {
                uint32_t w = bd[d][b];
                uint32_t q = (w | (w >> 9) | (w >> 18)) & 0x1FFu;       // col presence in band
                uint32_t u = (q & 0x49u) + ((q >> 1) & 0x49u) + ((q >> 2) & 0x49u); // cols-per-box at [3k,3k+1]
                uint32_t single = u & ~(u >> 1) & 0x49u;
                pnt[b] = q & (single * 7u);
            }
            bd[d][0] &= ~((pnt[1] | pnt[2]) * 0x40201u);
            bd[d][1] &= ~((pnt[0] | pnt[2]) * 0x40201u);
            bd[d][2] &= ~((pnt[0] | pnt[1]) * 0x40201u);
        }

        // ---------- unique 'h' (hidden single in row) ----------
        {
            uint32_t hid[9][3];
            uint32_t has[3] = {0,0,0};
            #pragma unroll
            for (int d = 0; d < 9; ++d)
                #pragma unroll
                for (int b = 0; b < 3; ++b) {
                    uint32_t w = bd[d][b], h = 0;
                    #pragma unroll
                    for (int r = 0; r < 3; ++r) {
                        uint32_t x = w & (0x1FFu << (9 * r));
                        h |= (x & (x - 1u)) ? 0u : x;                   // single bit (or 0) keeps
                    }
                    hid[d][b] = h;
                    has[b] |= h;
                }
            #pragma unroll
            for (int d = 0; d < 9; ++d)
                #pragma unroll
                for (int b = 0; b < 3; ++b)
                    bd[d][b] = (bd[d][b] & ~has[b]) | hid[d][b];
        }

        // ---------- unique 'v' (hidden single in column) ----------
        {
            uint32_t hid[9][3];
            uint32_t has[3] = {0,0,0};
            #pragma unroll
            for (int d = 0; d < 9; ++d) {
                uint32_t h0 = 0, h1 = 0, h2 = 0;
                #pragma unroll
                for (int c = 0; c < 9; ++c) {
                    uint32_t cm = 0x40201u << c;
                    uint32_t a0 = bd[d][0] & cm;
                    uint32_t a1 = bd[d][1] & cm;
                    uint32_t a2 = bd[d][2] & cm;
                    uint32_t cnt = (uint32_t)(__popc(a0) + __popc(a1) + __popc(a2));
                    uint32_t mm = (cnt == 1u) ? 0xFFFFFFFFu : 0u;
                    h0 |= a0 & mm; h1 |= a1 & mm; h2 |= a2 & mm;
                }
                hid[d][0] = h0; hid[d][1] = h1; hid[d][2] = h2;
                has[0] |= h0; has[1] |= h1; has[2] |= h2;
            }
            #pragma unroll
            for (int d = 0; d < 9; ++d)
                #pragma unroll
                for (int b = 0; b < 3; ++b)
                    bd[d][b] = (bd[d][b] & ~has[b]) | hid[d][b];
        }

        // ---------- unique 'box' (hidden single in box) ----------
        {
            uint32_t hid[9][3];
            uint32_t has[3] = {0,0,0};
            #pragma unroll
            for (int d = 0; d < 9; ++d)
                #pragma unroll
                for (int b = 0; b < 3; ++b) {
                    uint32_t w = bd[d][b], h = 0;
                    #pragma unroll
                    for (int k = 0; k < 3; ++k) {
                        uint32_t x = w & (0x1C0E07u << (3 * k));
                        h |= (x & (x - 1u)) ? 0u : x;
                    }
                    hid[d][b] = h;
                    has[b] |= h;
                }
            #pragma unroll
            for (int d = 0; d < 9; ++d)
                #pragma unroll
                for (int b = 0; b < 3; ++b)
                    bd[d][b] = (bd[d][b] & ~has[b]) | hid[d][b];
        }

        // ---------- doubles 'v' twice (naked pairs on columns) ----------
        for (int rep = 0; rep < 2; ++rep) {
            uint32_t on[3] = {0,0,0}, tw[3] = {0,0,0}, fo[3] = {0,0,0};
            #pragma unroll
            for (int d = 0; d < 9; ++d)
                #pragma unroll
                for (int b = 0; b < 3; ++b) {
                    uint32_t c = on[b] & bd[d][b];
                    on[b] ^= bd[d][b];
                    fo[b] |= tw[b] & c;
                    tw[b] ^= c;
                }
            uint32_t ex2[3], Q[9][3], K[9][3];
            #pragma unroll
            for (int b = 0; b < 3; ++b) ex2[b] = tw[b] & ~on[b] & ~fo[b];
            #pragma unroll
            for (int d = 0; d < 9; ++d)
                #pragma unroll
                for (int b = 0; b < 3; ++b) { Q[d][b] = bd[d][b] & ex2[b]; K[d][b] = 0u; }
            #pragma unroll
            for (int d1 = 0; d1 < 9; ++d1)
                #pragma unroll
                for (int d2 = d1 + 1; d2 < 9; ++d2) {
                    uint32_t P0 = Q[d1][0] & Q[d2][0];   // cells with pattern exactly {d1,d2}
                    uint32_t P1 = Q[d1][1] & Q[d2][1];
                    uint32_t P2 = Q[d1][2] & Q[d2][2];
                    uint32_t f0 = (P0 | (P0 >> 9) | (P0 >> 18)) & 0x1FFu;
                    uint32_t f1 = (P1 | (P1 >> 9) | (P1 >> 18)) & 0x1FFu;
                    uint32_t f2 = (P2 | (P2 >> 9) | (P2 >> 18)) & 0x1FFu;
                    uint32_t g0 = ((P0 & (P0 >> 9)) | ((P0 | (P0 >> 9)) & (P0 >> 18))) & 0x1FFu;
                    uint32_t g1 = ((P1 & (P1 >> 9)) | ((P1 | (P1 >> 9)) & (P1 >> 18))) & 0x1FFu;
                    uint32_t g2 = ((P2 & (P2 >> 9)) | ((P2 | (P2 >> 9)) & (P2 >> 18))) & 0x1FFu;
                    // columns with >=2 such cells: >=2 in one band, or presence in >=2 bands
                    uint32_t dup = g0 | g1 | g2 | (f0 & f1) | (f0 & f2) | (f1 & f2);
                    uint32_t em = dup * 0x40201u;
                    uint32_t s0 = P0 & em, s1 = P1 & em, s2 = P2 & em;
                    K[d1][0] |= s0; K[d1][1] |= s1; K[d1][2] |= s2;
                    K[d2][0] |= s0; K[d2][1] |= s1; K[d2][2] |= s2;
                }
            #pragma unroll
            for (int d = 0; d < 9; ++d) {
                uint32_t fold = K[d][0] | K[d][1] | K[d][2];
                uint32_t cols = (fold | (fold >> 9) | (fold >> 18)) & 0x1FFu;
                uint32_t em = cols * 0x40201u;
                #pragma unroll
                for (int b = 0; b < 3; ++b)
                    bd[d][b] = (bd[d][b] & ~em) | K[d][b];
            }
        }

        // ---------- doubles 'box' (naked pairs in boxes) ----------
        {
            uint32_t on[3] = {0,0,0}, tw[3] = {0,0,0}, fo[3] = {0,0,0};
            #pragma unroll
            for (int d = 0; d < 9; ++d)
                #pragma unroll
                for (int b = 0; b < 3; ++b) {
                    uint32_t c = on[b] & bd[d][b];
                    on[b] ^= bd[d][b];
                    fo[b] |= tw[b] & c;
                    tw[b] ^= c;
                }
            uint32_t ex2[3], Q[9][3], K[9][3];
            #pragma unroll
            for (int b = 0; b < 3; ++b) ex2[b] = tw[b] & ~on[b] & ~fo[b];
            #pragma unroll
            for (int d = 0; d < 9; ++d)
                #pragma unroll
                for (int b = 0; b < 3; ++b) { Q[d][b] = bd[d][b] & ex2[b]; K[d][b] = 0u; }
            #pragma unroll
            for (int d1 = 0; d1 < 9; ++d1)
                #pragma unroll
                for (int d2 = d1 + 1; d2 < 9; ++d2)
                    #pragma unroll
                    for (int b = 0; b < 3; ++b) {
                        uint32_t P = Q[d1][b] & Q[d2][b];
                        #pragma unroll
                        for (int k = 0; k < 3; ++k) {
                            uint32_t m = P & (0x1C0E07u << (3 * k));
                            uint32_t s = (m & (m - 1u)) ? m : 0u;   // >=2 cells in the box
                            K[d1][b] |= s; K[d2][b] |= s;
                        }
                    }
            #pragma unroll
            for (int d = 0; d < 9; ++d)
                #pragma unroll
                for (int b = 0; b < 3; ++b)
                    #pragma unroll
                    for (int k = 0; k < 3; ++k) {
                        uint32_t bm = 0x1C0E07u << (3 * k);
                        uint32_t t = K[d][b] & bm;
                        uint32_t mask = t ? (~bm | t) : 0xFFFFFFFFu;
                        bd[d][b] &= mask;
                    }
        }
    } // passes

    // store packed result
    {
        uint32_t* dst = pout + (size_t)p * 27;
        #pragma unroll
        for (int i = 0; i < 27; ++i) dst[i] = bd[i / 3][i % 3];
    }
    // solved flag: every cell has exactly one candidate
    {
        uint32_t on[3] = {0,0,0}, tw[3] = {0,0,0}, fo[3] = {0,0,0};
        #pragma unroll
        for (int d = 0; d < 9; ++d)
            #pragma unroll
            for (int b = 0; b < 3; ++b) {
                uint32_t c = on[b] & bd[d][b];
                on[b] ^= bd[d][b];
                fo[b] |= tw[b] & c;
                tw[b] ^= c;
            }
        bool ok = ((on[0] & ~tw[0] & ~fo[0]) == FULL27) &&
                  ((on[1] & ~tw[1] & ~fo[1]) == FULL27) &&
                  ((on[2] & ~tw[2] & ~fo[2]) == FULL27);
        solved[p] = ok ? 1.0f : 0.0f;
    }
}

__global__ void expand_kernel(const uint32_t* __restrict__ packed, float* __restrict__ out) {
    int i = blockIdx.x * blockDim.x + threadIdx.x;
    if (i >= NB * 729) return;
    int p = i / 729;
    int j = i - p * 729;
    int q = j / 27;
    int pos = j - q * 27;
    uint32_t w = packed[p * 27 + q];
    out[i] = (float)((w >> pos) & 1u);
}

extern "C" void kernel_launch(void* const* d_in, const int* in_sizes, int n_in,
                              void* d_out, int out_size, void* d_ws, size_t ws_size,
                              hipStream_t stream) {
    const uint32_t* in = (const uint32_t*)d_in[0];   // float32 bits; nonzero <=> 1.0f
    float* out = (float*)d_out;
    float* solved = out + (size_t)NB * 729;
    uint32_t* packed = (uint32_t*)d_ws;              // NB*27 words = 3.54 MB

    int nw = NB * 27;                                // 884736 words, /256 = 3456 blocks exact
    pack_kernel<<<nw / 256, 256, 0, stream>>>(in, packed);
    // solve reads then overwrites its own 27 words: safe in-place
    solve_kernel<<<(NB + 63) / 64, 64, 0, stream>>>(packed, packed, solved);
    int ne = NB * 729;
    expand_kernel<<<(ne + 255) / 256, 256, 0, stream>>>(packed, out);
}